// Round 2
// baseline (1916.494 us; speedup 1.0000x reference)
//
#include <hip/hip_runtime.h>
#include <hip/hip_fp16.h>

#define N_NODES 100000
#define N_EDGES 1600000
#define F_IN 128
#define OUT 32
#define PERIODS 12

// ---------------- prep: M = W @ L_top, cc = b @ L_top + lb, probs = softmax(att)
__global__ void k_prep(const float* __restrict__ Wz, const float* __restrict__ bz,
                       const float* __restrict__ Lz, const float* __restrict__ lbz,
                       const float* __restrict__ Wh, const float* __restrict__ bh,
                       const float* __restrict__ Lh, const float* __restrict__ lbh,
                       const float* __restrict__ att,
                       float* __restrict__ M, float* __restrict__ cc,
                       float* __restrict__ probs) {
    int t = threadIdx.x;
    // M layout: [128][64], c<32 -> Mz column c, c>=32 -> Mh column c-32
    for (int idx = t; idx < F_IN * 64; idx += 256) {
        int f = idx >> 6, c = idx & 63;
        const float* W = (c < 32) ? Wz : Wh;
        const float* L = (c < 32) ? Lz : Lh;
        int cj = c & 31;
        float s = 0.f;
        #pragma unroll 8
        for (int j = 0; j < 32; ++j) s += W[f * 32 + j] * L[j * 32 + cj];
        M[idx] = s;
    }
    if (t < 64) {
        int c = t & 31;
        const float* b  = (t < 32) ? bz : bh;
        const float* L  = (t < 32) ? Lz : Lh;
        const float* lb = (t < 32) ? lbz : lbh;
        float s = lb[c];
        for (int j = 0; j < 32; ++j) s += b[j] * L[j * 32 + c];
        cc[t] = s;
    }
    if (t == 0) {
        float m = att[0];
        for (int p = 1; p < PERIODS; ++p) m = fmaxf(m, att[p]);
        float e[PERIODS]; float sum = 0.f;
        for (int p = 0; p < PERIODS; ++p) { e[p] = expf(att[p] - m); sum += e[p]; }
        for (int p = 0; p < PERIODS; ++p) probs[p] = e[p] / sum;
    }
}

// ---------------- in-degree count (targets = edge_index[1], int32 on device)
__global__ void k_count(const int* __restrict__ ei, int* __restrict__ cnt) {
    int e = blockIdx.x * 256 + threadIdx.x;
    if (e < N_EDGES) {
        int c = ei[N_EDGES + e];
        if ((unsigned)c < N_NODES) atomicAdd(&cnt[c], 1);
    }
}

// ---------------- dis = rsqrt(indeg + 1)   (self-loop always present -> deg >= 1)
__global__ void k_dis(const int* __restrict__ cnt, float* __restrict__ dis) {
    int i = blockIdx.x * 256 + threadIdx.x;
    if (i < N_NODES) dis[i] = rsqrtf((float)(cnt[i] + 1));
}

// ---------------- 3-kernel exclusive scan of cnt -> rp
__global__ void k_scan1(const int* __restrict__ cnt, int* __restrict__ rp,
                        int* __restrict__ partials) {
    __shared__ int s[256];
    int t = threadIdx.x;
    int i = blockIdx.x * 256 + t;
    int v = (i < N_NODES) ? cnt[i] : 0;
    s[t] = v;
    __syncthreads();
    for (int off = 1; off < 256; off <<= 1) {
        int y = (t >= off) ? s[t - off] : 0;
        __syncthreads();
        s[t] += y;
        __syncthreads();
    }
    if (i < N_NODES) rp[i] = s[t] - v;          // exclusive, pre-offset
    if (t == 255) partials[blockIdx.x] = s[255]; // block total
}

__global__ void k_scan2(int* __restrict__ partials, int np) {
    __shared__ int s[512];
    int t = threadIdx.x;
    int v = (t < np) ? partials[t] : 0;
    s[t] = v;
    __syncthreads();
    for (int off = 1; off < 512; off <<= 1) {
        int y = (t >= off) ? s[t - off] : 0;
        __syncthreads();
        s[t] += y;
        __syncthreads();
    }
    if (t < np) partials[t] = s[t] - v;          // exclusive
}

__global__ void k_scan3(int* __restrict__ rp, const int* __restrict__ partials) {
    int i = blockIdx.x * 256 + threadIdx.x;
    if (i < N_NODES) rp[i] += partials[blockIdx.x];
    if (i == 0) rp[N_NODES] = N_EDGES;
}

// ---------------- CSR fill: srcIdx grouped by target
__global__ void k_fill(const int* __restrict__ ei, const int* __restrict__ rp,
                       int* __restrict__ cursor, int* __restrict__ srcIdx) {
    int e = blockIdx.x * 256 + threadIdx.x;
    if (e < N_EDGES) {
        int c = ei[N_EDGES + e];
        int r = ei[e];
        if ((unsigned)c < N_NODES) {
            int pos = rp[c] + atomicAdd(&cursor[c], 1);
            srcIdx[pos] = r;
        }
    }
}

// ---------------- projection: U[n][p*64+c] = sum_f x[n][f][p] * M[f][c]   (fp16 out)
__global__ void k_proj(const float* __restrict__ x, const float* __restrict__ M,
                       __half* __restrict__ U) {
    int wave = threadIdx.x >> 6;
    int lane = threadIdx.x & 63;            // c
    int n = blockIdx.x * 4 + wave;
    if (n >= N_NODES) return;
    const float4* xf = reinterpret_cast<const float4*>(x + (size_t)n * (F_IN * PERIODS));
    float acc[PERIODS];
    #pragma unroll
    for (int p = 0; p < PERIODS; ++p) acc[p] = 0.f;
    #pragma unroll 2
    for (int f = 0; f < F_IN; ++f) {
        float m = M[f * 64 + lane];
        float4 a = xf[f * 3 + 0];
        float4 b = xf[f * 3 + 1];
        float4 c4 = xf[f * 3 + 2];
        acc[0] += a.x * m;  acc[1] += a.y * m;  acc[2]  += a.z * m;  acc[3]  += a.w * m;
        acc[4] += b.x * m;  acc[5] += b.y * m;  acc[6]  += b.z * m;  acc[7]  += b.w * m;
        acc[8] += c4.x * m; acc[9] += c4.y * m; acc[10] += c4.z * m; acc[11] += c4.w * m;
    }
    __half* un = U + (size_t)n * 768;
    #pragma unroll
    for (int p = 0; p < PERIODS; ++p) un[p * 64 + lane] = __float2half(acc[p]);
}

// ---------------- fused aggregate + TGCN cell + attention sum + head
// block = 192 threads, one node per block; thread t owns halves [4t, 4t+4)
__global__ void k_agg(const __half* __restrict__ U, const int* __restrict__ rp,
                      const int* __restrict__ srcIdx, const float* __restrict__ dis,
                      const float* __restrict__ cc, const float* __restrict__ probs,
                      const float* __restrict__ Wlin, const float* __restrict__ blin,
                      float* __restrict__ out) {
    int n = blockIdx.x;
    int t = threadIdx.x;          // 0..191
    float dn = dis[n];

    float a0, a1, a2, a3;
    {   // self-loop: weight dis[n]^2
        union { uint2 u; __half2 h[2]; } r;
        r.u = reinterpret_cast<const uint2*>(U + (size_t)n * 768)[t];
        float2 f0 = __half22float2(r.h[0]);
        float2 f1 = __half22float2(r.h[1]);
        float w = dn * dn;
        a0 = w * f0.x; a1 = w * f0.y; a2 = w * f1.x; a3 = w * f1.y;
    }
    int beg = rp[n], end = rp[n + 1];
    for (int e = beg; e < end; ++e) {
        int s = srcIdx[e];
        float w = dis[s] * dn;
        union { uint2 u; __half2 h[2]; } r;
        r.u = reinterpret_cast<const uint2*>(U + (size_t)s * 768)[t];
        float2 f0 = __half22float2(r.h[0]);
        float2 f1 = __half22float2(r.h[1]);
        a0 += w * f0.x; a1 += w * f0.y; a2 += w * f1.x; a3 += w * f1.y;
    }

    __shared__ float sacc[768];
    __shared__ float sterm[PERIODS * 32];
    __shared__ float shf[32];
    sacc[4 * t + 0] = a0; sacc[4 * t + 1] = a1;
    sacc[4 * t + 2] = a2; sacc[4 * t + 3] = a3;
    __syncthreads();

    // gate: term[p][c] = probs[p] * (1 - sigmoid(z)) * tanh(h)
    for (int w2 = t; w2 < PERIODS * 32; w2 += 192) {
        int p = w2 >> 5, c = w2 & 31;
        float z = sacc[p * 64 + c]      + cc[c];
        float h = sacc[p * 64 + 32 + c] + cc[32 + c];
        float zs = 1.f / (1.f + __expf(-z));
        sterm[w2] = probs[p] * (1.f - zs) * tanhf(h);
    }
    __syncthreads();

    if (t < 32) {
        float s = 0.f;
        #pragma unroll
        for (int p = 0; p < PERIODS; ++p) s += sterm[p * 32 + t];
        shf[t] = fmaxf(s, 0.f);           // relu(acc)
    }
    __syncthreads();

    if (t < PERIODS) {
        float o = blin[t];
        #pragma unroll 8
        for (int c = 0; c < OUT; ++c) o += shf[c] * Wlin[c * PERIODS + t];
        out[(size_t)n * PERIODS + t] = o;
    }
}

extern "C" void kernel_launch(void* const* d_in, const int* in_sizes, int n_in,
                              void* d_out, int out_size, void* d_ws, size_t ws_size,
                              hipStream_t stream) {
    const float* x    = (const float*)d_in[0];
    const int*   ei   = (const int*)d_in[1];      // int64 in reference -> int32 on device
    const float* Wz   = (const float*)d_in[2];
    const float* bz   = (const float*)d_in[3];
    const float* Lz   = (const float*)d_in[4];
    const float* lbz  = (const float*)d_in[5];
    const float* Wh   = (const float*)d_in[6];
    const float* bh   = (const float*)d_in[7];
    const float* Lh   = (const float*)d_in[8];
    const float* lbh  = (const float*)d_in[9];
    const float* att  = (const float*)d_in[10];
    const float* Wlin = (const float*)d_in[11];
    const float* blin = (const float*)d_in[12];
    float* out = (float*)d_out;

    char* w = (char*)d_ws;
    size_t off = 0;
    __half* U      = (__half*)(w + off); off += (size_t)N_NODES * 768 * 2; // 153.6 MB
    float*  M      = (float*)(w + off);  off += 128 * 64 * 4;
    float*  cc     = (float*)(w + off);  off += 256;
    float*  probs  = (float*)(w + off);  off += 64;
    float*  dis    = (float*)(w + off);  off += N_NODES * 4;
    int*    cnt    = (int*)(w + off);    off += N_NODES * 4;
    int*    rp     = (int*)(w + off);    off += (N_NODES + 1) * 4 + 12;
    int*    cursor = (int*)(w + off);    off += N_NODES * 4;
    int*    parts  = (int*)(w + off);    off += 2048;
    int*    srcIdx = (int*)(w + off);    off += (size_t)N_EDGES * 4;
    (void)ws_size; (void)in_sizes; (void)n_in; (void)out_size;

    const int SCAN_BLOCKS = (N_NODES + 255) / 256; // 391

    hipMemsetAsync(cnt, 0, N_NODES * 4, stream);
    hipMemsetAsync(cursor, 0, N_NODES * 4, stream);

    k_prep<<<1, 256, 0, stream>>>(Wz, bz, Lz, lbz, Wh, bh, Lh, lbh, att, M, cc, probs);
    k_count<<<(N_EDGES + 255) / 256, 256, 0, stream>>>(ei, cnt);
    k_dis<<<SCAN_BLOCKS, 256, 0, stream>>>(cnt, dis);
    k_scan1<<<SCAN_BLOCKS, 256, 0, stream>>>(cnt, rp, parts);
    k_scan2<<<1, 512, 0, stream>>>(parts, SCAN_BLOCKS);
    k_scan3<<<SCAN_BLOCKS, 256, 0, stream>>>(rp, parts);
    k_fill<<<(N_EDGES + 255) / 256, 256, 0, stream>>>(ei, rp, cursor, srcIdx);
    k_proj<<<N_NODES / 4, 256, 0, stream>>>(x, M, U);
    k_agg<<<N_NODES, 192, 0, stream>>>(U, rp, srcIdx, dis, cc, probs, Wlin, blin, out);
}

// Round 3
// 913.019 us; speedup vs baseline: 2.0991x; 2.0991x over previous
//
#include <hip/hip_runtime.h>
#include <hip/hip_fp16.h>

#define N_NODES 100000
#define N_EDGES 1600000
#define F_IN 128
#define OUT 32
#define PERIODS 12

// ---------------- prep: M = W @ L_top, cc = b @ L_top + lb, probs = softmax(att)
__global__ void k_prep(const float* __restrict__ Wz, const float* __restrict__ bz,
                       const float* __restrict__ Lz, const float* __restrict__ lbz,
                       const float* __restrict__ Wh, const float* __restrict__ bh,
                       const float* __restrict__ Lh, const float* __restrict__ lbh,
                       const float* __restrict__ att,
                       float* __restrict__ M, float* __restrict__ cc,
                       float* __restrict__ probs) {
    int t = threadIdx.x;
    // M layout: [128][64], c<32 -> Mz column c, c>=32 -> Mh column c-32
    for (int idx = t; idx < F_IN * 64; idx += 256) {
        int f = idx >> 6, c = idx & 63;
        const float* W = (c < 32) ? Wz : Wh;
        const float* L = (c < 32) ? Lz : Lh;
        int cj = c & 31;
        float s = 0.f;
        #pragma unroll 8
        for (int j = 0; j < 32; ++j) s += W[f * 32 + j] * L[j * 32 + cj];
        M[idx] = s;
    }
    if (t < 64) {
        int c = t & 31;
        const float* b  = (t < 32) ? bz : bh;
        const float* L  = (t < 32) ? Lz : Lh;
        const float* lb = (t < 32) ? lbz : lbh;
        float s = lb[c];
        for (int j = 0; j < 32; ++j) s += b[j] * L[j * 32 + c];
        cc[t] = s;
    }
    if (t == 0) {
        float m = att[0];
        for (int p = 1; p < PERIODS; ++p) m = fmaxf(m, att[p]);
        float e[PERIODS]; float sum = 0.f;
        for (int p = 0; p < PERIODS; ++p) { e[p] = expf(att[p] - m); sum += e[p]; }
        for (int p = 0; p < PERIODS; ++p) probs[p] = e[p] / sum;
    }
}

// ---------------- in-degree count (targets = edge_index[1], int32 on device)
__global__ void k_count(const int* __restrict__ ei, int* __restrict__ cnt) {
    int e = blockIdx.x * 256 + threadIdx.x;
    if (e < N_EDGES) {
        int c = ei[N_EDGES + e];
        if ((unsigned)c < N_NODES) atomicAdd(&cnt[c], 1);
    }
}

// ---------------- dis = rsqrt(indeg + 1)
__global__ void k_dis(const int* __restrict__ cnt, float* __restrict__ dis) {
    int i = blockIdx.x * 256 + threadIdx.x;
    if (i < N_NODES) dis[i] = rsqrtf((float)(cnt[i] + 1));
}

// ---------------- 3-kernel exclusive scan of cnt -> rp
__global__ void k_scan1(const int* __restrict__ cnt, int* __restrict__ rp,
                        int* __restrict__ partials) {
    __shared__ int s[256];
    int t = threadIdx.x;
    int i = blockIdx.x * 256 + t;
    int v = (i < N_NODES) ? cnt[i] : 0;
    s[t] = v;
    __syncthreads();
    for (int off = 1; off < 256; off <<= 1) {
        int y = (t >= off) ? s[t - off] : 0;
        __syncthreads();
        s[t] += y;
        __syncthreads();
    }
    if (i < N_NODES) rp[i] = s[t] - v;
    if (t == 255) partials[blockIdx.x] = s[255];
}

__global__ void k_scan2(int* __restrict__ partials, int np) {
    __shared__ int s[512];
    int t = threadIdx.x;
    int v = (t < np) ? partials[t] : 0;
    s[t] = v;
    __syncthreads();
    for (int off = 1; off < 512; off <<= 1) {
        int y = (t >= off) ? s[t - off] : 0;
        __syncthreads();
        s[t] += y;
        __syncthreads();
    }
    if (t < np) partials[t] = s[t] - v;
}

__global__ void k_scan3(int* __restrict__ rp, const int* __restrict__ partials) {
    int i = blockIdx.x * 256 + threadIdx.x;
    if (i < N_NODES) rp[i] += partials[blockIdx.x];
    if (i == 0) rp[N_NODES] = N_EDGES;
}

// ---------------- CSR fill
__global__ void k_fill(const int* __restrict__ ei, const int* __restrict__ rp,
                       int* __restrict__ cursor, int* __restrict__ srcIdx) {
    int e = blockIdx.x * 256 + threadIdx.x;
    if (e < N_EDGES) {
        int c = ei[N_EDGES + e];
        int r = ei[e];
        if ((unsigned)c < N_NODES) {
            int pos = rp[c] + atomicAdd(&cursor[c], 1);
            srcIdx[pos] = r;
        }
    }
}

// ---------------- projection v2: LDS-tiled, register-blocked
// block=256 (4 waves), 16 nodes/block; lane = output col c, wave = node group.
// U[n][p*64+c] = sum_f x[n][f][p] * M[f][c], stored fp16.
__global__ __launch_bounds__(256, 2) void k_proj2(const float* __restrict__ x,
                                                  const float* __restrict__ M,
                                                  __half* __restrict__ U) {
    __shared__ float sM[F_IN * 64];        // 32 KB
    __shared__ float4 sx[16 * 48];         // 16 nodes x 192 floats = 12 KB
    int t = threadIdx.x;
    int lane = t & 63;
    int wv = t >> 6;                       // 0..3 node group

    // stage M once (2048 float4)
    {
        const float4* Mv = reinterpret_cast<const float4*>(M);
        float4* sMv = reinterpret_cast<float4*>(sM);
        #pragma unroll
        for (int i = 0; i < 8; ++i) sMv[t + 256 * i] = Mv[t + 256 * i];
    }

    int nb0 = blockIdx.x * 16;
    float acc[4][PERIODS];
    #pragma unroll
    for (int a = 0; a < 4; ++a)
        #pragma unroll
        for (int p = 0; p < PERIODS; ++p) acc[a][p] = 0.f;

    const float4* xg = reinterpret_cast<const float4*>(x) + (size_t)nb0 * 384;

    for (int kc = 0; kc < 8; ++kc) {
        __syncthreads();                   // prev compute done (also covers sM on kc=0)
        // stage 16 nodes x 48 float4 (f in [kc*16, kc*16+16), all 12 p)
        #pragma unroll
        for (int i = 0; i < 3; ++i) {
            int j = t + 256 * i;           // 0..767
            int node = j / 48;
            int within = j - node * 48;
            sx[j] = xg[(size_t)node * 384 + kc * 48 + within];
        }
        __syncthreads();
        #pragma unroll
        for (int f = 0; f < 16; ++f) {
            float m = sM[(kc * 16 + f) * 64 + lane];
            #pragma unroll
            for (int nn = 0; nn < 4; ++nn) {
                int base = (wv * 4 + nn) * 48 + f * 3;
                float4 xa = sx[base];
                float4 xb = sx[base + 1];
                float4 xc = sx[base + 2];
                acc[nn][0]  += xa.x * m; acc[nn][1]  += xa.y * m;
                acc[nn][2]  += xa.z * m; acc[nn][3]  += xa.w * m;
                acc[nn][4]  += xb.x * m; acc[nn][5]  += xb.y * m;
                acc[nn][6]  += xb.z * m; acc[nn][7]  += xb.w * m;
                acc[nn][8]  += xc.x * m; acc[nn][9]  += xc.y * m;
                acc[nn][10] += xc.z * m; acc[nn][11] += xc.w * m;
            }
        }
    }

    #pragma unroll
    for (int nn = 0; nn < 4; ++nn) {
        __half* un = U + (size_t)(nb0 + wv * 4 + nn) * 768;
        #pragma unroll
        for (int p = 0; p < PERIODS; ++p) un[p * 64 + lane] = __float2half(acc[nn][p]);
    }
}

// ---------------- fused aggregate + TGCN cell + attention sum + head
// block = 192 threads, one node per block; thread t owns halves [4t, 4t+4)
__global__ void k_agg(const __half* __restrict__ U, const int* __restrict__ rp,
                      const int* __restrict__ srcIdx, const float* __restrict__ dis,
                      const float* __restrict__ cc, const float* __restrict__ probs,
                      const float* __restrict__ Wlin, const float* __restrict__ blin,
                      float* __restrict__ out) {
    int n = blockIdx.x;
    int t = threadIdx.x;          // 0..191
    float dn = dis[n];

    float a0, a1, a2, a3;
    {   // self-loop: weight dis[n]^2
        union { uint2 u; __half2 h[2]; } r;
        r.u = reinterpret_cast<const uint2*>(U + (size_t)n * 768)[t];
        float2 f0 = __half22float2(r.h[0]);
        float2 f1 = __half22float2(r.h[1]);
        float w = dn * dn;
        a0 = w * f0.x; a1 = w * f0.y; a2 = w * f1.x; a3 = w * f1.y;
    }
    int beg = rp[n], end = rp[n + 1];
    int e = beg;
    for (; e + 1 < end; e += 2) {          // unroll x2 for MLP on dependent chain
        int s0 = srcIdx[e];
        int s1 = srcIdx[e + 1];
        float w0 = dis[s0] * dn;
        float w1 = dis[s1] * dn;
        union { uint2 u; __half2 h[2]; } r0, r1;
        r0.u = reinterpret_cast<const uint2*>(U + (size_t)s0 * 768)[t];
        r1.u = reinterpret_cast<const uint2*>(U + (size_t)s1 * 768)[t];
        float2 a = __half22float2(r0.h[0]);
        float2 b = __half22float2(r0.h[1]);
        a0 += w0 * a.x; a1 += w0 * a.y; a2 += w0 * b.x; a3 += w0 * b.y;
        float2 c = __half22float2(r1.h[0]);
        float2 d = __half22float2(r1.h[1]);
        a0 += w1 * c.x; a1 += w1 * c.y; a2 += w1 * d.x; a3 += w1 * d.y;
    }
    if (e < end) {
        int s = srcIdx[e];
        float w = dis[s] * dn;
        union { uint2 u; __half2 h[2]; } r;
        r.u = reinterpret_cast<const uint2*>(U + (size_t)s * 768)[t];
        float2 f0 = __half22float2(r.h[0]);
        float2 f1 = __half22float2(r.h[1]);
        a0 += w * f0.x; a1 += w * f0.y; a2 += w * f1.x; a3 += w * f1.y;
    }

    __shared__ float sacc[768];
    __shared__ float sterm[PERIODS * 32];
    __shared__ float shf[32];
    sacc[4 * t + 0] = a0; sacc[4 * t + 1] = a1;
    sacc[4 * t + 2] = a2; sacc[4 * t + 3] = a3;
    __syncthreads();

    for (int w2 = t; w2 < PERIODS * 32; w2 += 192) {
        int p = w2 >> 5, c = w2 & 31;
        float z = sacc[p * 64 + c]      + cc[c];
        float h = sacc[p * 64 + 32 + c] + cc[32 + c];
        float zs = 1.f / (1.f + __expf(-z));
        sterm[w2] = probs[p] * (1.f - zs) * tanhf(h);
    }
    __syncthreads();

    if (t < 32) {
        float s = 0.f;
        #pragma unroll
        for (int p = 0; p < PERIODS; ++p) s += sterm[p * 32 + t];
        shf[t] = fmaxf(s, 0.f);
    }
    __syncthreads();

    if (t < PERIODS) {
        float o = blin[t];
        #pragma unroll 8
        for (int c = 0; c < OUT; ++c) o += shf[c] * Wlin[c * PERIODS + t];
        out[(size_t)n * PERIODS + t] = o;
    }
}

extern "C" void kernel_launch(void* const* d_in, const int* in_sizes, int n_in,
                              void* d_out, int out_size, void* d_ws, size_t ws_size,
                              hipStream_t stream) {
    const float* x    = (const float*)d_in[0];
    const int*   ei   = (const int*)d_in[1];
    const float* Wz   = (const float*)d_in[2];
    const float* bz   = (const float*)d_in[3];
    const float* Lz   = (const float*)d_in[4];
    const float* lbz  = (const float*)d_in[5];
    const float* Wh   = (const float*)d_in[6];
    const float* bh   = (const float*)d_in[7];
    const float* Lh   = (const float*)d_in[8];
    const float* lbh  = (const float*)d_in[9];
    const float* att  = (const float*)d_in[10];
    const float* Wlin = (const float*)d_in[11];
    const float* blin = (const float*)d_in[12];
    float* out = (float*)d_out;

    char* w = (char*)d_ws;
    size_t off = 0;
    __half* U      = (__half*)(w + off); off += (size_t)N_NODES * 768 * 2; // 153.6 MB
    float*  M      = (float*)(w + off);  off += 128 * 64 * 4;
    float*  cc     = (float*)(w + off);  off += 256;
    float*  probs  = (float*)(w + off);  off += 64;
    float*  dis    = (float*)(w + off);  off += N_NODES * 4;
    int*    cnt    = (int*)(w + off);    off += N_NODES * 4;
    int*    rp     = (int*)(w + off);    off += (N_NODES + 1) * 4 + 12;
    int*    cursor = (int*)(w + off);    off += N_NODES * 4;
    int*    parts  = (int*)(w + off);    off += 2048;
    int*    srcIdx = (int*)(w + off);    off += (size_t)N_EDGES * 4;
    (void)ws_size; (void)in_sizes; (void)n_in; (void)out_size;

    const int SCAN_BLOCKS = (N_NODES + 255) / 256; // 391

    hipMemsetAsync(cnt, 0, N_NODES * 4, stream);
    hipMemsetAsync(cursor, 0, N_NODES * 4, stream);

    k_prep<<<1, 256, 0, stream>>>(Wz, bz, Lz, lbz, Wh, bh, Lh, lbh, att, M, cc, probs);
    k_count<<<(N_EDGES + 255) / 256, 256, 0, stream>>>(ei, cnt);
    k_dis<<<SCAN_BLOCKS, 256, 0, stream>>>(cnt, dis);
    k_scan1<<<SCAN_BLOCKS, 256, 0, stream>>>(cnt, rp, parts);
    k_scan2<<<1, 512, 0, stream>>>(parts, SCAN_BLOCKS);
    k_scan3<<<SCAN_BLOCKS, 256, 0, stream>>>(rp, parts);
    k_fill<<<(N_EDGES + 255) / 256, 256, 0, stream>>>(ei, rp, cursor, srcIdx);
    k_proj2<<<N_NODES / 16, 256, 0, stream>>>(x, M, U);
    k_agg<<<N_NODES, 192, 0, stream>>>(U, rp, srcIdx, dis, cc, probs, Wlin, blin, out);
}

// Round 4
// 809.290 us; speedup vs baseline: 2.3681x; 1.1282x over previous
//
#include <hip/hip_runtime.h>
#include <hip/hip_fp16.h>

#define N_NODES 100000
#define N_EDGES 1600000
#define F_IN 128
#define OUT 32
#define PERIODS 12

// ---------------- prep: M = W @ L_top, cc = b @ L_top + lb, probs = softmax(att)
__global__ void k_prep(const float* __restrict__ Wz, const float* __restrict__ bz,
                       const float* __restrict__ Lz, const float* __restrict__ lbz,
                       const float* __restrict__ Wh, const float* __restrict__ bh,
                       const float* __restrict__ Lh, const float* __restrict__ lbh,
                       const float* __restrict__ att,
                       float* __restrict__ M, float* __restrict__ cc,
                       float* __restrict__ probs) {
    int t = threadIdx.x;
    // M layout: [128][64], c<32 -> Mz column c, c>=32 -> Mh column c-32
    for (int idx = t; idx < F_IN * 64; idx += 256) {
        int f = idx >> 6, c = idx & 63;
        const float* W = (c < 32) ? Wz : Wh;
        const float* L = (c < 32) ? Lz : Lh;
        int cj = c & 31;
        float s = 0.f;
        #pragma unroll 8
        for (int j = 0; j < 32; ++j) s += W[f * 32 + j] * L[j * 32 + cj];
        M[idx] = s;
    }
    if (t < 64) {
        int c = t & 31;
        const float* b  = (t < 32) ? bz : bh;
        const float* L  = (t < 32) ? Lz : Lh;
        const float* lb = (t < 32) ? lbz : lbh;
        float s = lb[c];
        for (int j = 0; j < 32; ++j) s += b[j] * L[j * 32 + c];
        cc[t] = s;
    }
    if (t == 0) {
        float m = att[0];
        for (int p = 1; p < PERIODS; ++p) m = fmaxf(m, att[p]);
        float e[PERIODS]; float sum = 0.f;
        for (int p = 0; p < PERIODS; ++p) { e[p] = expf(att[p] - m); sum += e[p]; }
        for (int p = 0; p < PERIODS; ++p) probs[p] = e[p] / sum;
    }
}

// ---------------- in-degree count (targets = edge_index[1], int32 on device)
__global__ void k_count(const int* __restrict__ ei, int* __restrict__ cnt) {
    int e = blockIdx.x * 256 + threadIdx.x;
    if (e < N_EDGES) {
        int c = ei[N_EDGES + e];
        if ((unsigned)c < N_NODES) atomicAdd(&cnt[c], 1);
    }
}

// ---------------- dis = rsqrt(indeg + 1)
__global__ void k_dis(const int* __restrict__ cnt, float* __restrict__ dis) {
    int i = blockIdx.x * 256 + threadIdx.x;
    if (i < N_NODES) dis[i] = rsqrtf((float)(cnt[i] + 1));
}

// ---------------- 3-kernel exclusive scan of cnt -> rp
__global__ void k_scan1(const int* __restrict__ cnt, int* __restrict__ rp,
                        int* __restrict__ partials) {
    __shared__ int s[256];
    int t = threadIdx.x;
    int i = blockIdx.x * 256 + t;
    int v = (i < N_NODES) ? cnt[i] : 0;
    s[t] = v;
    __syncthreads();
    for (int off = 1; off < 256; off <<= 1) {
        int y = (t >= off) ? s[t - off] : 0;
        __syncthreads();
        s[t] += y;
        __syncthreads();
    }
    if (i < N_NODES) rp[i] = s[t] - v;
    if (t == 255) partials[blockIdx.x] = s[255];
}

__global__ void k_scan2(int* __restrict__ partials, int np) {
    __shared__ int s[512];
    int t = threadIdx.x;
    int v = (t < np) ? partials[t] : 0;
    s[t] = v;
    __syncthreads();
    for (int off = 1; off < 512; off <<= 1) {
        int y = (t >= off) ? s[t - off] : 0;
        __syncthreads();
        s[t] += y;
        __syncthreads();
    }
    if (t < np) partials[t] = s[t] - v;
}

__global__ void k_scan3(int* __restrict__ rp, const int* __restrict__ partials) {
    int i = blockIdx.x * 256 + threadIdx.x;
    if (i < N_NODES) rp[i] += partials[blockIdx.x];
    if (i == 0) rp[N_NODES] = N_EDGES;
}

// ---------------- CSR fill
__global__ void k_fill(const int* __restrict__ ei, const int* __restrict__ rp,
                       int* __restrict__ cursor, int* __restrict__ srcIdx) {
    int e = blockIdx.x * 256 + threadIdx.x;
    if (e < N_EDGES) {
        int c = ei[N_EDGES + e];
        int r = ei[e];
        if ((unsigned)c < N_NODES) {
            int pos = rp[c] + atomicAdd(&cursor[c], 1);
            srcIdx[pos] = r;
        }
    }
}

// ---------------- projection v3: c-quad per thread, VALU-bound 2:1 FMA:LDS
// block=256, 16 nodes/block; thread t: node = t>>4, c-quad = 4*(t&15).
// Per f: 1 b128 M-read + 3 b128 x-reads -> 48 FMAs.
__global__ __launch_bounds__(256, 3) void k_proj3(const float* __restrict__ x,
                                                  const float* __restrict__ M,
                                                  __half* __restrict__ U) {
    __shared__ float sM[F_IN * 64];        // 32 KB
    __shared__ float4 sx[16 * 49];         // 49 float4/node (pad) = 12.25 KB
    int t = threadIdx.x;
    int cidx = t & 15;                     // c quad = [4*cidx, 4*cidx+4)
    int node = t >> 4;                     // 0..15

    {   // stage M once (2048 float4)
        const float4* Mv = reinterpret_cast<const float4*>(M);
        float4* sMv = reinterpret_cast<float4*>(sM);
        #pragma unroll
        for (int i = 0; i < 8; ++i) sMv[t + 256 * i] = Mv[t + 256 * i];
    }

    int nb0 = blockIdx.x * 16;
    float acc[4][PERIODS];
    #pragma unroll
    for (int c = 0; c < 4; ++c)
        #pragma unroll
        for (int p = 0; p < PERIODS; ++p) acc[c][p] = 0.f;

    const float4* xg = reinterpret_cast<const float4*>(x) + (size_t)nb0 * 384;

    for (int kc = 0; kc < 8; ++kc) {
        __syncthreads();                   // prev compute done (covers sM on kc=0)
        // stage 16 nodes x 48 float4 (f in [kc*16, kc*16+16), all 12 p)
        #pragma unroll
        for (int i = 0; i < 3; ++i) {
            int j = t + 256 * i;           // 0..767
            int nd = j / 48;
            int wi = j - nd * 48;
            sx[nd * 49 + wi] = xg[(size_t)nd * 384 + kc * 48 + wi];
        }
        __syncthreads();
        #pragma unroll
        for (int f = 0; f < 16; ++f) {
            float4 m4 = *reinterpret_cast<const float4*>(&sM[(kc * 16 + f) * 64 + 4 * cidx]);
            int xb = node * 49 + f * 3;
            float4 xv0 = sx[xb];
            float4 xv1 = sx[xb + 1];
            float4 xv2 = sx[xb + 2];
            float mm[4] = {m4.x, m4.y, m4.z, m4.w};
            float xv[PERIODS] = {xv0.x, xv0.y, xv0.z, xv0.w,
                                 xv1.x, xv1.y, xv1.z, xv1.w,
                                 xv2.x, xv2.y, xv2.z, xv2.w};
            #pragma unroll
            for (int c = 0; c < 4; ++c)
                #pragma unroll
                for (int p = 0; p < PERIODS; ++p)
                    acc[c][p] += mm[c] * xv[p];
        }
    }

    __half* un = U + (size_t)(nb0 + node) * 768 + 4 * cidx;
    #pragma unroll
    for (int p = 0; p < PERIODS; ++p) {
        __half2 h0 = __floats2half2_rn(acc[0][p], acc[1][p]);
        __half2 h1 = __floats2half2_rn(acc[2][p], acc[3][p]);
        union { uint2 u; __half2 h[2]; } r;
        r.h[0] = h0; r.h[1] = h1;
        *reinterpret_cast<uint2*>(un + p * 64) = r.u;
    }
}

// ---------------- fused aggregate + TGCN cell + attention sum + head
// block = 192 threads, one node per block; thread t owns halves [4t, 4t+4)
__global__ void k_agg(const __half* __restrict__ U, const int* __restrict__ rp,
                      const int* __restrict__ srcIdx, const float* __restrict__ dis,
                      const float* __restrict__ cc, const float* __restrict__ probs,
                      const float* __restrict__ Wlin, const float* __restrict__ blin,
                      float* __restrict__ out) {
    int n = blockIdx.x;
    int t = threadIdx.x;          // 0..191
    float dn = dis[n];

    float a0, a1, a2, a3;
    {   // self-loop: weight dis[n]^2
        union { uint2 u; __half2 h[2]; } r;
        r.u = reinterpret_cast<const uint2*>(U + (size_t)n * 768)[t];
        float2 f0 = __half22float2(r.h[0]);
        float2 f1 = __half22float2(r.h[1]);
        float w = dn * dn;
        a0 = w * f0.x; a1 = w * f0.y; a2 = w * f1.x; a3 = w * f1.y;
    }
    int beg = rp[n], end = rp[n + 1];
    int e = beg;
    for (; e + 1 < end; e += 2) {
        int s0 = srcIdx[e];
        int s1 = srcIdx[e + 1];
        float w0 = dis[s0] * dn;
        float w1 = dis[s1] * dn;
        union { uint2 u; __half2 h[2]; } r0, r1;
        r0.u = reinterpret_cast<const uint2*>(U + (size_t)s0 * 768)[t];
        r1.u = reinterpret_cast<const uint2*>(U + (size_t)s1 * 768)[t];
        float2 a = __half22float2(r0.h[0]);
        float2 b = __half22float2(r0.h[1]);
        a0 += w0 * a.x; a1 += w0 * a.y; a2 += w0 * b.x; a3 += w0 * b.y;
        float2 c = __half22float2(r1.h[0]);
        float2 d = __half22float2(r1.h[1]);
        a0 += w1 * c.x; a1 += w1 * c.y; a2 += w1 * d.x; a3 += w1 * d.y;
    }
    if (e < end) {
        int s = srcIdx[e];
        float w = dis[s] * dn;
        union { uint2 u; __half2 h[2]; } r;
        r.u = reinterpret_cast<const uint2*>(U + (size_t)s * 768)[t];
        float2 f0 = __half22float2(r.h[0]);
        float2 f1 = __half22float2(r.h[1]);
        a0 += w * f0.x; a1 += w * f0.y; a2 += w * f1.x; a3 += w * f1.y;
    }

    __shared__ float sacc[768];
    __shared__ float sterm[PERIODS * 32];
    __shared__ float shf[32];
    sacc[4 * t + 0] = a0; sacc[4 * t + 1] = a1;
    sacc[4 * t + 2] = a2; sacc[4 * t + 3] = a3;
    __syncthreads();

    for (int w2 = t; w2 < PERIODS * 32; w2 += 192) {
        int p = w2 >> 5, c = w2 & 31;
        float z = sacc[p * 64 + c]      + cc[c];
        float h = sacc[p * 64 + 32 + c] + cc[32 + c];
        float zs = 1.f / (1.f + __expf(-z));
        sterm[w2] = probs[p] * (1.f - zs) * tanhf(h);
    }
    __syncthreads();

    if (t < 32) {
        float s = 0.f;
        #pragma unroll
        for (int p = 0; p < PERIODS; ++p) s += sterm[p * 32 + t];
        shf[t] = fmaxf(s, 0.f);
    }
    __syncthreads();

    if (t < PERIODS) {
        float o = blin[t];
        #pragma unroll 8
        for (int c = 0; c < OUT; ++c) o += shf[c] * Wlin[c * PERIODS + t];
        out[(size_t)n * PERIODS + t] = o;
    }
}

extern "C" void kernel_launch(void* const* d_in, const int* in_sizes, int n_in,
                              void* d_out, int out_size, void* d_ws, size_t ws_size,
                              hipStream_t stream) {
    const float* x    = (const float*)d_in[0];
    const int*   ei   = (const int*)d_in[1];
    const float* Wz   = (const float*)d_in[2];
    const float* bz   = (const float*)d_in[3];
    const float* Lz   = (const float*)d_in[4];
    const float* lbz  = (const float*)d_in[5];
    const float* Wh   = (const float*)d_in[6];
    const float* bh   = (const float*)d_in[7];
    const float* Lh   = (const float*)d_in[8];
    const float* lbh  = (const float*)d_in[9];
    const float* att  = (const float*)d_in[10];
    const float* Wlin = (const float*)d_in[11];
    const float* blin = (const float*)d_in[12];
    float* out = (float*)d_out;

    char* w = (char*)d_ws;
    size_t off = 0;
    __half* U      = (__half*)(w + off); off += (size_t)N_NODES * 768 * 2; // 153.6 MB
    float*  M      = (float*)(w + off);  off += 128 * 64 * 4;
    float*  cc     = (float*)(w + off);  off += 256;
    float*  probs  = (float*)(w + off);  off += 64;
    float*  dis    = (float*)(w + off);  off += N_NODES * 4;
    int*    cnt    = (int*)(w + off);    off += N_NODES * 4;
    int*    rp     = (int*)(w + off);    off += (N_NODES + 1) * 4 + 12;
    int*    cursor = (int*)(w + off);    off += N_NODES * 4;
    int*    parts  = (int*)(w + off);    off += 2048;
    int*    srcIdx = (int*)(w + off);    off += (size_t)N_EDGES * 4;
    (void)ws_size; (void)in_sizes; (void)n_in; (void)out_size;

    const int SCAN_BLOCKS = (N_NODES + 255) / 256; // 391

    hipMemsetAsync(cnt, 0, N_NODES * 4, stream);
    hipMemsetAsync(cursor, 0, N_NODES * 4, stream);

    k_prep<<<1, 256, 0, stream>>>(Wz, bz, Lz, lbz, Wh, bh, Lh, lbh, att, M, cc, probs);
    k_count<<<(N_EDGES + 255) / 256, 256, 0, stream>>>(ei, cnt);
    k_dis<<<SCAN_BLOCKS, 256, 0, stream>>>(cnt, dis);
    k_scan1<<<SCAN_BLOCKS, 256, 0, stream>>>(cnt, rp, parts);
    k_scan2<<<1, 512, 0, stream>>>(parts, SCAN_BLOCKS);
    k_scan3<<<SCAN_BLOCKS, 256, 0, stream>>>(rp, parts);
    k_fill<<<(N_EDGES + 255) / 256, 256, 0, stream>>>(ei, rp, cursor, srcIdx);
    k_proj3<<<N_NODES / 16, 256, 0, stream>>>(x, M, U);
    k_agg<<<N_NODES, 192, 0, stream>>>(U, rp, srcIdx, dis, cc, probs, Wlin, blin, out);
}